// Round 10
// baseline (13.592 us; speedup 1.0000x reference)
//
#include <hip/hip_runtime.h>

// DocumentBertScoringLoss: loss = MSE + MR + SIM over B=8192 fp32 vectors.
// MR term == mean over all (m,n) of max(0, 0.1 - |p_m - p_n|) (verified r1).
// Identity:  sum max(0, 0.1-|d|)  =  0.1*B^2 - sum min(|d|, 0.1)   (exact).
//
// Structure history (measured):
//   r1 two-kernel scalar-LDS pairwise: 18.4 us
//   r2 ticket + 4-byte memset node: 27.4 us. DEAD END (39us fill node).
//   r3 cooperative grid.sync(): 104 us/dispatch. DEAD END.
//   r4 two-kernel, float4-LDS f32, uniform: 15.6 us.
//   r6 triangle + divergent band tiles: 21.7 us. DEAD END (stragglers).
//   r7 two-kernel, packed-f16 min-trick, uniform: 14.8 us.
//   r8 fused ticket: 26.5 us. DEAD END (per-block device fence cost; and
//      mask-ticket is racy for unaligned poison start -- unsafe, not just slow).
//   r9 512 blocks + light finalize: 13.3 us (best).
// r10: make pairwise FULLY uniform (drop by==0 linear branch; dispatch time is
//      max over blocks). Linear terms move to finalize, which reads p,g
//      directly (64 KB, L2-hot) and fuses all 5 reductions into one wave-fold
//      + a single __syncthreads. linPartial eliminated.

#define B_N 8192
#define THREADS 256
#define M_PER_THREAD 2
#define MB (THREADS * M_PER_THREAD)   // 512 m-rows per block
#define NXB (B_N / MB)                // 16 m-chunks
#define CHUNK 256                     // n's staged in LDS per block
#define NYB (B_N / CHUNK)             // 32 n-chunks
#define NBLOCKS (NXB * NYB)           // 512 blocks = 2/CU exactly

typedef _Float16 h8 __attribute__((ext_vector_type(8)));

__device__ __forceinline__ float block_reduce_sum(float v, float* sbuf) {
    #pragma unroll
    for (int off = 32; off > 0; off >>= 1)
        v += __shfl_down(v, off, 64);
    const int lane = threadIdx.x & 63;
    const int wave = threadIdx.x >> 6;
    if (lane == 0) sbuf[wave] = v;
    __syncthreads();
    if (threadIdx.x == 0) {
        float s = 0.f;
        #pragma unroll
        for (int w = 0; w < THREADS / 64; ++w) s += sbuf[w];
        sbuf[0] = s;
    }
    __syncthreads();
    const float r = sbuf[0];
    __syncthreads();
    return r;
}

__global__ void __launch_bounds__(THREADS)
pairwise_kernel(const float* __restrict__ p,
                float* __restrict__ pairPartial) {   // [NBLOCKS]
    __shared__ alignas(16) _Float16 s_h[CHUNK];
    __shared__ float sbuf[THREADS / 64];

    const int tid = threadIdx.x;
    const int m0 = blockIdx.x * MB + tid;       // coalesced
    const float pm0f = p[m0];
    const float pm1f = p[m0 + THREADS];

    s_h[tid] = (_Float16)p[blockIdx.y * CHUNK + tid];   // CHUNK == THREADS
    __syncthreads();

    // Branch-free packed-f16 loop: acc += min(|pm - v|, 0.1) per element.
    // Per h8 per row: 4x v_pk_sub, 2-4x v_and (abs), 4x v_pk_min, 4x v_pk_add.
    const h8* s8 = (const h8*)s_h;
    const _Float16 pm0s = (_Float16)pm0f;
    const _Float16 pm1s = (_Float16)pm1f;
    const h8 pm0 = {pm0s, pm0s, pm0s, pm0s, pm0s, pm0s, pm0s, pm0s};
    const h8 pm1 = {pm1s, pm1s, pm1s, pm1s, pm1s, pm1s, pm1s, pm1s};
    const _Float16 bs = (_Float16)0.1f;
    const h8 bias = {bs, bs, bs, bs, bs, bs, bs, bs};
    h8 acc0 = {0, 0, 0, 0, 0, 0, 0, 0};
    h8 acc1 = {0, 0, 0, 0, 0, 0, 0, 0};
    #pragma unroll
    for (int j = 0; j < CHUNK / 8; ++j) {       // 32 x ds_read_b128 (broadcast)
        const h8 v = s8[j];
        acc0 += __builtin_elementwise_min(__builtin_elementwise_abs(pm0 - v), bias);
        acc1 += __builtin_elementwise_min(__builtin_elementwise_abs(pm1 - v), bias);
    }
    const h8 a = acc0 + acc1;                   // each lane <= 6.4, f16-safe
    float minsum = 0.f;
    #pragma unroll
    for (int k = 0; k < 8; ++k) minsum += (float)a[k];

    const float s = block_reduce_sum(minsum, sbuf);
    if (tid == 0) pairPartial[blockIdx.y * NXB + blockIdx.x] = s;
}

__global__ void __launch_bounds__(THREADS)
finalize_kernel(const float* __restrict__ p, const float* __restrict__ g,
                const float* __restrict__ pairPartial,
                float* __restrict__ out) {
    __shared__ float  sbufm[THREADS / 64];
    __shared__ float4 sbuf4[THREADS / 64];

    const int tid = threadIdx.x;

    // Pairwise partials: 512 floats, one float2 per thread.
    const float2* pp2 = (const float2*)pairPartial;
    const float2 v2 = pp2[tid];
    float minsum = v2.x + v2.y;

    // Linear terms recomputed here (64 KB, L2-hot): 8 float4's per thread.
    float sq = 0.f, dot = 0.f, npp = 0.f, ngg = 0.f;
    const float4* p4 = (const float4*)p;
    const float4* g4 = (const float4*)g;
    #pragma unroll
    for (int k = 0; k < B_N / 4 / THREADS; ++k) {   // 8 iters
        const float4 a = p4[tid + k * THREADS];
        const float4 b = g4[tid + k * THREADS];
        const float d0 = a.x - b.x, d1 = a.y - b.y, d2 = a.z - b.z, d3 = a.w - b.w;
        sq  += d0 * d0 + d1 * d1 + d2 * d2 + d3 * d3;
        dot += a.x * b.x + a.y * b.y + a.z * b.z + a.w * b.w;
        npp += a.x * a.x + a.y * a.y + a.z * a.z + a.w * a.w;
        ngg += b.x * b.x + b.y * b.y + b.z * b.z + b.w * b.w;
    }

    // Fused 5-value reduction: wave fold, one LDS roundtrip, one barrier.
    #pragma unroll
    for (int off = 32; off > 0; off >>= 1) {
        minsum += __shfl_down(minsum, off, 64);
        sq     += __shfl_down(sq, off, 64);
        dot    += __shfl_down(dot, off, 64);
        npp    += __shfl_down(npp, off, 64);
        ngg    += __shfl_down(ngg, off, 64);
    }
    const int lane = tid & 63;
    const int wave = tid >> 6;
    if (lane == 0) {
        sbufm[wave] = minsum;
        sbuf4[wave] = make_float4(sq, dot, npp, ngg);
    }
    __syncthreads();

    if (tid == 0) {
        float ms = 0.f, lsq = 0.f, ldot = 0.f, lnpp = 0.f, lngg = 0.f;
        #pragma unroll
        for (int w = 0; w < THREADS / 64; ++w) {
            ms   += sbufm[w];
            lsq  += sbuf4[w].x;
            ldot += sbuf4[w].y;
            lnpp += sbuf4[w].z;
            lngg += sbuf4[w].w;
        }
        const float mse = lsq / (float)B_N;
        const float mrm = 0.1f - ms / ((float)B_N * (float)B_N);
        const float denom = fmaxf(sqrtf(lnpp) * sqrtf(lngg), 1e-8f);
        const float sim = 1.f - ldot / denom;
        out[0] = mse + mrm + sim;               // alpha = beta = gamma = 1
    }
}

extern "C" void kernel_launch(void* const* d_in, const int* in_sizes, int n_in,
                              void* d_out, int out_size, void* d_ws, size_t ws_size,
                              hipStream_t stream) {
    const float* p = (const float*)d_in[0];
    const float* g = (const float*)d_in[1];
    float* pairPartial = (float*)d_ws;   // 512 floats, all rewritten each call

    dim3 grid(NXB, NYB);
    pairwise_kernel<<<grid, THREADS, 0, stream>>>(p, pairPartial);
    finalize_kernel<<<1, THREADS, 0, stream>>>(p, g, pairPartial, (float*)d_out);
}